// Round 8
// baseline (152.477 us; speedup 1.0000x reference)
//
#include <hip/hip_runtime.h>
#include <math.h>

// CRITICAL: ban FMA contraction file-wide. 1-ulp iou shifts flip near-tie
// argmaxes vs numpy's correctly-rounded ref (rounds 2-4, absmax 69).
#pragma clang fp contract(off)

// Shapes: B=64, N=100, A=8732.
// Out layout (f32 flat): [0,BA) labels | [BA,5BA) boxes | [5BA,6BA) mask
// colmax u64[B*N] at out+BA (boxes region): init by prior_kernel, atomicMax'd
// by iou_pass, consumed by scatter, overwritten by encode.
// d_ws: prior float[B*N] = 25,600 B (proven-safe size).

#define AA 8732
#define NN 100
#define BB 64
#define EPS_F 1e-6f
#define OVR_FLAG 0x10000
// Deflation for one-sided bounds: qa = inter*v_rcp(uni) has rel err <=
// ~1.8e-7 (rcp 1 ulp + mul 0.5 ulp). 5e-7 margin => qa < t*DEFL proves
// iou < t rigorously.
#define DEFL 0.9999995f

__constant__ int FM_SIZE[6] = {38, 19, 10, 5, 3, 1};
__constant__ int FM_NF[6]   = {4, 6, 6, 6, 4, 4};
__constant__ int FM_OFF[6]  = {0, 5776, 7942, 8542, 8692, 8728};

__device__ __forceinline__ float iou_exact(float4 an, float4 g,
                                           float area_a, float area_g) {
    float ltx = fmaxf(an.x, g.x);
    float lty = fmaxf(an.y, g.y);
    float rbx = fminf(an.z, g.z);
    float rby = fminf(an.w, g.w);
    float w = fmaxf(rbx - ltx, 0.0f);
    float h = fmaxf(rby - lty, 0.0f);
    float inter = w * h;
    return inter / (area_a + area_g - inter);   // exact IEEE == numpy
}

// ---------------------------------------------------------------------------
// Prior: per (b,n), max IoU over the <=30 anchors at the gt-center cell of
// each feature map — a genuine column iou => SAFE lower bound of column max.
// Also initializes colmax with (prior_bits<<32 | lowkey=0): any real
// candidate (lowkey>=1, bits>=prior) beats it; lowkey=0 is rejected by
// scatter's guard if (impossibly) nothing contributes.
// ---------------------------------------------------------------------------
__global__ void prior_kernel(const float4* __restrict__ gt_boxes,
                             const float4* __restrict__ anchors_xyxy,
                             float* __restrict__ prior,
                             unsigned long long* __restrict__ colmax) {
    const int b = blockIdx.x;
    const int n = threadIdx.x;
    if (n >= NN) return;
    float4 g = gt_boxes[b * NN + n];
    float area_g = (g.z - g.x) * (g.w - g.y);
    float cx = (g.x + g.z) * 0.5f;
    float cy = (g.y + g.w) * 0.5f;
    float best = 0.0f;
    for (int f = 0; f < 6; f++) {
        int s = FM_SIZE[f];
        int j = (int)(cx * (float)s); j = j < s - 1 ? j : s - 1;
        int i = (int)(cy * (float)s); i = i < s - 1 ? i : s - 1;
        int base = FM_OFF[f] + (i * s + j) * FM_NF[f];
        for (int k = 0; k < FM_NF[f]; k++) {
            float4 an = anchors_xyxy[base + k];
            float area_a = (an.z - an.x) * (an.w - an.y);
            best = fmaxf(best, iou_exact(an, g, area_a, area_g));
        }
    }
    prior[b * NN + n] = best;
    colmax[b * NN + n] = ((unsigned long long)__float_as_uint(best)) << 32;
}

// ---------------------------------------------------------------------------
// Fused IoU pass, two-phase:
// Phase A (branch-free): qa = inter*v_rcp(uni) upper-ish bound; wave-uniform
//   scalar mask bit_n = __any(near-record OR >= column filter). Scalar-pipe
//   mask build — no VALU cost, no branches, dense FP pipelining.
// Phase B: visit flagged n ascending (ctz) — re-test vs final am*DEFL /
//   scurf[n]; only then pay the exact IEEE divide (sole decision-maker),
//   row update (strict >, ascending => np first occurrence), column wave
//   reduce + packed u64 atomicMax ((bits<<32)|(AA-a): max iou, then lowest a).
// Candidate-set proof: iou==rowmax => qa >= M(1-1.8e-7) while the running
//   am*DEFL <= M(1+1.8e-7)(1-5e-7) < M(1-1.8e-7) => flagged; same margin
//   for the B-retest and for column (scurf deflated genuine ious). qa>0
//   excludes zero rows (bi=0 init == np argmax of all-zero row).
// ---------------------------------------------------------------------------
__global__ __launch_bounds__(256) void iou_pass_kernel(
        const float4* __restrict__ gt_boxes,        // B*N xyxy
        const float4* __restrict__ anchors_xyxy,    // A
        const float* __restrict__ prior,            // B*N
        unsigned long long* __restrict__ colmax,    // B*N packed, init by prior
        float* __restrict__ out_val,                // -> out[0..BA)
        int* __restrict__ out_slot)                 // -> out[5BA..6BA)
{
    const int b = blockIdx.y;
    const int tid = threadIdx.x;
    const int a = blockIdx.x * 256 + tid;
    const bool valid = (a < AA);
    const int ac = valid ? a : (AA - 1);

    __shared__ float4 sg[NN];
    __shared__ float  sarea[NN];
    __shared__ float  scurf[NN];   // deflated genuine column lower bounds

    if (tid < NN) {
        float4 g = gt_boxes[b * NN + tid];
        sg[tid] = g;
        sarea[tid] = (g.z - g.x) * (g.w - g.y);
        scurf[tid] = prior[b * NN + tid] * DEFL;
    }
    __syncthreads();

    const float4 axy = anchors_xyxy[ac];
    const float area_a = (axy.z - axy.x) * (axy.w - axy.y);

    // ---------------- Phase A ----------------
    float am = 0.0f;                       // running max of qa
    unsigned long long wmLo = 0ull, wmHi = 0ull;

    #pragma unroll 4
    for (int n = 0; n < 64; n++) {
        float4 g = sg[n];
        float ag = sarea[n];
        float ltx = fmaxf(axy.x, g.x);
        float lty = fmaxf(axy.y, g.y);
        float rbx = fminf(axy.z, g.z);
        float rby = fminf(axy.w, g.w);
        float w = fmaxf(rbx - ltx, 0.0f);
        float h = fmaxf(rby - lty, 0.0f);
        float inter = w * h;
        float uni = area_a + ag - inter;
        float qa = inter * __builtin_amdgcn_rcpf(uni);
        bool r = (qa > 0.0f) && (qa >= am * DEFL);
        bool c = valid && (qa >= scurf[n]);
        am = fmaxf(am, qa);
        unsigned long long wf = (unsigned long long)__any((int)(r | c));
        wmLo |= wf << n;                   // uniform: scalar-pipe shifts/ors
    }
    #pragma unroll 4
    for (int n = 64; n < NN; n++) {
        float4 g = sg[n];
        float ag = sarea[n];
        float ltx = fmaxf(axy.x, g.x);
        float lty = fmaxf(axy.y, g.y);
        float rbx = fminf(axy.z, g.z);
        float rby = fminf(axy.w, g.w);
        float w = fmaxf(rbx - ltx, 0.0f);
        float h = fmaxf(rby - lty, 0.0f);
        float inter = w * h;
        float uni = area_a + ag - inter;
        float qa = inter * __builtin_amdgcn_rcpf(uni);
        bool r = (qa > 0.0f) && (qa >= am * DEFL);
        bool c = valid && (qa >= scurf[n]);
        am = fmaxf(am, qa);
        unsigned long long wf = (unsigned long long)__any((int)(r | c));
        wmHi |= wf << (n - 64);
    }

    // ---------------- Phase B ----------------
    const float amthr = am * DEFL;
    float bv = 0.0f;   // all-zero row: bv=0, bi=0 == numpy
    int bi = 0;

    #pragma unroll 1
    for (int half = 0; half < 2; half++) {
        unsigned long long wm = half ? wmHi : wmLo;
        const int nbase = half ? 64 : 0;
        while (wm) {
            int n = __builtin_ctzll(wm) + nbase;   // ascending n: np order
            wm &= wm - 1;
            float4 g = sg[n];
            float ag = sarea[n];
            float ltx = fmaxf(axy.x, g.x);
            float lty = fmaxf(axy.y, g.y);
            float rbx = fminf(axy.z, g.z);
            float rby = fminf(axy.w, g.w);
            float w = fmaxf(rbx - ltx, 0.0f);
            float h = fmaxf(rby - lty, 0.0f);
            float inter = w * h;
            float uni = area_a + ag - inter;
            float qa = inter * __builtin_amdgcn_rcpf(uni);
            bool rc = (qa > 0.0f) && (qa >= amthr);
            bool cc = valid && (qa >= scurf[n]);
            if (__any((int)(rc | cc))) {
                float iou = inter / uni;            // exact IEEE == numpy
                if (iou > bv) { bv = iou; bi = n; } // strict >: first max
                if (__any((int)cc)) {
                    unsigned qb = valid ? __float_as_uint(iou) : 0u;
                    unsigned m = qb;
                    #pragma unroll
                    for (int off = 32; off > 0; off >>= 1) {
                        unsigned o = __shfl_xor(m, off);
                        m = o > m ? o : m;
                    }
                    unsigned long long ball = __ballot((int)(qb == m && m > 0u));
                    if (ball) {
                        int leader = __ffsll((long long)ball) - 1; // lowest a
                        if ((tid & 63) == leader) {
                            unsigned long long v =
                                (((unsigned long long)m) << 32) |
                                (unsigned long long)(unsigned)(AA - a);
                            atomicMax(colmax + b * NN + n, v);
                            atomicMax((unsigned*)&scurf[n],
                                      __float_as_uint(__uint_as_float(m) * DEFL));
                        }
                    }
                }
            }
        }
    }

    if (valid) {
        const size_t base = (size_t)b * AA + a;
        out_val[base] = bv;
        out_slot[base] = bi;
    }
}

// ---------------------------------------------------------------------------
// Scatter gt->anchor override: np fancy-assignment last-n-wins ==
// atomicMax over (OVR_FLAG + n). lowkey==0 (prior sentinel) rejected.
// ---------------------------------------------------------------------------
__global__ void scatter_kernel(const unsigned long long* __restrict__ colmax,
                               int* __restrict__ out_slot) {
    const int b = blockIdx.x;
    const int n = threadIdx.x;
    if (n < NN) {
        unsigned long long v = colmax[b * NN + n];
        unsigned low = (unsigned)(v & 0xFFFFFFFFull);
        if (low >= 1u && low <= (unsigned)AA) {
            int idx = AA - (int)low;
            atomicMax(&out_slot[(size_t)b * AA + idx], OVR_FLAG + n);
        }
    }
}

// ---------------------------------------------------------------------------
// Encode: read row val/slot, apply override, encode boxes, write outputs.
// ---------------------------------------------------------------------------
__global__ __launch_bounds__(256) void encode_kernel(
        const int* __restrict__ gt_labels,
        const float4* __restrict__ gt_boxes,        // xyxy
        const float4* __restrict__ anchors_cxcywh,
        float* __restrict__ out)
{
    const int b = blockIdx.y;
    const int tid = threadIdx.x;
    const int a = blockIdx.x * 256 + tid;

    __shared__ float4 sg[NN];
    __shared__ int    slab[NN];
    if (tid < NN) {
        sg[tid]   = gt_boxes[b * NN + tid];
        slab[tid] = gt_labels[b * NN + tid];
    }
    __syncthreads();
    if (a >= AA) return;

    const size_t BA = (size_t)BB * AA;
    const size_t base = (size_t)b * AA + a;

    float bv = out[base];
    int s = ((const int*)(out + 5 * BA))[base];

    int idx; float val;
    if (s >= OVR_FLAG) { idx = s - OVR_FLAG; val = 2.0f; }
    else               { idx = s;            val = bv;   }
    const bool pos = val > 0.5f;

    const float4 g = sg[idx];
    const float gcx = (g.x + g.z) * 0.5f;
    const float gcy = (g.y + g.w) * 0.5f;
    const float gw  = g.z - g.x;
    const float gh  = g.w - g.y;

    const float4 anc = anchors_cxcywh[a];
    const float ecx = (gcx - anc.x) / anc.z;
    const float ecy = (gcy - anc.y) / anc.w;
    const float ew  = logf((gw + EPS_F) / (anc.z + EPS_F));
    const float eh  = logf((gh + EPS_F) / (anc.w + EPS_F));

    out[base] = pos ? (float)slab[idx] : 0.0f;                   // labels
    ((float4*)(out + BA))[base] = make_float4(ecx, ecy, ew, eh); // boxes
    out[5 * BA + base] = pos ? 1.0f : 0.0f;                      // mask
}

extern "C" void kernel_launch(void* const* d_in, const int* in_sizes, int n_in,
                              void* d_out, int out_size, void* d_ws, size_t ws_size,
                              hipStream_t stream) {
    const int*    gt_labels    = (const int*)d_in[0];
    const float4* gt_boxes     = (const float4*)d_in[1];
    const float4* anchors_cxcy = (const float4*)d_in[2];
    const float4* anchors_xyxy = (const float4*)d_in[3];
    float* out = (float*)d_out;

    const size_t BA = (size_t)BB * AA;
    unsigned long long* colmax = (unsigned long long*)(out + BA); // 8B-aligned
    int* slot = (int*)(out + 5 * BA);
    float* prior = (float*)d_ws;        // B*N floats = 25,600 B (proven size)

    prior_kernel<<<BB, 128, 0, stream>>>(gt_boxes, anchors_xyxy, prior, colmax);

    dim3 grid((AA + 255) / 256, BB);
    iou_pass_kernel<<<grid, 256, 0, stream>>>(gt_boxes, anchors_xyxy, prior,
                                              colmax, out, slot);
    scatter_kernel<<<BB, 128, 0, stream>>>(colmax, slot);
    encode_kernel<<<grid, 256, 0, stream>>>(gt_labels, gt_boxes, anchors_cxcy, out);
}

// Round 10
// 145.485 us; speedup vs baseline: 1.0481x; 1.0481x over previous
//
#include <hip/hip_runtime.h>
#include <math.h>

// CRITICAL: ban FMA contraction file-wide. 1-ulp iou shifts flip near-tie
// argmaxes vs numpy's correctly-rounded ref (rounds 2-4, absmax 69).
#pragma clang fp contract(off)

// Shapes: B=64, N=100, A=8732.
// Out layout (f32 flat): [0,BA) labels | [BA,5BA) boxes | [5BA,6BA) mask
// iou_pass writes: row max iou -> labels region, row argmax -> mask region.
// colmax u64[B*N] at out+BA (boxes region): memset to 0, atomicMax'd by
// iou_pass, consumed by scatter, then boxes region overwritten by encode.
// d_ws unused.

#define AA 8732
#define NN 100
#define BB 64
#define EPS_F 1e-6f
#define OVR_FLAG 0x10000
// qa = inter*v_rcp(uni) has rel err <= ~1.8e-7 (rcp 1 ulp + mul 0.5 ulp).
// DEFL=1-5e-7 deflation makes all filters rigorous one-sided bounds
// (candidate-set safety validated on HW in round 8).
#define DEFL 0.9999995f

__constant__ int FM_SIZE[6] = {38, 19, 10, 5, 3, 1};
__constant__ int FM_NF[6]   = {4, 6, 6, 6, 4, 4};
__constant__ int FM_OFF[6]  = {0, 5776, 7942, 8542, 8692, 8728};

__device__ __forceinline__ void geom(const float4 axy, const float4 g,
                                     float area_a, float ag,
                                     float& inter, float& uni) {
    float ltx = fmaxf(axy.x, g.x);
    float lty = fmaxf(axy.y, g.y);
    float rbx = fminf(axy.z, g.z);
    float rby = fminf(axy.w, g.w);
    float w = fmaxf(rbx - ltx, 0.0f);
    float h = fmaxf(rby - lty, 0.0f);
    inter = w * h;
    uni = area_a + ag - inter;       // uni >= max area > 0 always
}

// Phase A over [N0,N1): approx qa, per-lane row-record mask, per-lane
// column-candidate mask. No divides, no per-iter wave ops.
template <int N0, int N1>
__device__ __forceinline__ void phaseA(const float4 axy, float area_a,
                                       bool valid,
                                       const float4* sg, const float* sarea,
                                       const float* scurf,
                                       float& am, unsigned& rm, unsigned& cm) {
    #pragma unroll 4
    for (int n = N0; n < N1; n++) {
        float inter, uni;
        geom(axy, sg[n], area_a, sarea[n], inter, uni);
        float qa = inter * __builtin_amdgcn_rcpf(uni);
        bool r = (qa > 0.0f) && (qa >= am * DEFL);   // row near-record
        bool c = valid && (qa >= scurf[n]);          // column candidate
        am = fmaxf(am, qa);
        rm |= (r ? 1u : 0u) << (n - N0);
        cm |= (c ? 1u : 0u) << (n - N0);
    }
}

// ---------------------------------------------------------------------------
// Fused IoU pass:
//  - in-block prior (rcp-based, deflated): scurf[n] = safe lower bound of
//    column max from the <=30 center-cell anchors of gt n
//  - Phase A: branch-free approx pass building per-lane masks
//  - Phase B row: walk own record bits, retest vs final am*DEFL, exact
//    IEEE div only for survivors (sole decision-maker); ascending n +
//    strict > == numpy first occurrence
//  - Phase B col: wave-OR'd candidate bits; exact div + u32 wave max over
//    cc lanes, leader (lowest tied lane = lowest a) does packed u64
//    atomicMax ((bits<<32)|(AA-a): max iou then lowest a) + scurf warm-up
// ---------------------------------------------------------------------------
__global__ __launch_bounds__(256) void iou_pass_kernel(
        const float4* __restrict__ gt_boxes,        // B*N xyxy
        const float4* __restrict__ anchors_xyxy,    // A
        unsigned long long* __restrict__ colmax,    // B*N packed, pre-zeroed
        float* __restrict__ out_val,                // -> out[0..BA)
        int* __restrict__ out_slot)                 // -> out[5BA..6BA)
{
    const int b = blockIdx.y;
    const int tid = threadIdx.x;
    const int a = blockIdx.x * 256 + tid;
    const bool valid = (a < AA);
    const int ac = valid ? a : (AA - 1);

    __shared__ float4 sg[NN];
    __shared__ float  sarea[NN];
    __shared__ float  scurf[NN];   // deflated genuine column lower bounds

    if (tid < NN) {
        float4 g = gt_boxes[b * NN + tid];
        sg[tid] = g;
        float ag = (g.z - g.x) * (g.w - g.y);
        sarea[tid] = ag;
        // in-block prior: center-cell anchors of each feature map (genuine
        // column ious, approx-deflated => safe lower bound of column max)
        float cx = (g.x + g.z) * 0.5f;
        float cy = (g.y + g.w) * 0.5f;
        float best = 0.0f;
        for (int f = 0; f < 6; f++) {
            int s = FM_SIZE[f];
            int j = (int)(cx * (float)s); j = j < s - 1 ? j : s - 1;
            int i = (int)(cy * (float)s); i = i < s - 1 ? i : s - 1;
            int base = FM_OFF[f] + (i * s + j) * FM_NF[f];
            for (int k = 0; k < FM_NF[f]; k++) {
                float4 an = anchors_xyxy[base + k];
                float area_a = (an.z - an.x) * (an.w - an.y);
                float inter, uni;
                geom(an, g, area_a, ag, inter, uni);
                best = fmaxf(best, inter * __builtin_amdgcn_rcpf(uni));
            }
        }
        scurf[tid] = best * DEFL;
    }
    __syncthreads();

    const float4 axy = anchors_xyxy[ac];
    const float area_a = (axy.z - axy.x) * (axy.w - axy.y);

    // ---------------- Phase A ----------------
    float am = 0.0f;
    unsigned rm0 = 0, rm1 = 0, rm2 = 0, rm3 = 0;
    unsigned cm0 = 0, cm1 = 0, cm2 = 0, cm3 = 0;
    phaseA<0, 32>(axy, area_a, valid, sg, sarea, scurf, am, rm0, cm0);
    phaseA<32, 64>(axy, area_a, valid, sg, sarea, scurf, am, rm1, cm1);
    phaseA<64, 96>(axy, area_a, valid, sg, sarea, scurf, am, rm2, cm2);
    phaseA<96, NN>(axy, area_a, valid, sg, sarea, scurf, am, rm3, cm3);

    // ---------------- Phase B: row (per-lane, ~5 bits, ~1-2 divides) ------
    const float amthr = am * DEFL;
    float bv = 0.0f;   // all-zero row: bv=0, bi=0 == numpy argmax
    int bi = 0;
    {
        unsigned rms[4] = {rm0, rm1, rm2, rm3};
        #pragma unroll
        for (int h = 0; h < 4; h++) {
            unsigned m = rms[h];
            const int nb = h * 32;
            while (m) {
                int n = __builtin_ctz(m) + nb;   // ascending n: numpy order
                m &= m - 1;
                float inter, uni;
                geom(axy, sg[n], area_a, sarea[n], inter, uni);
                float qa = inter * __builtin_amdgcn_rcpf(uni);
                if (qa > 0.0f && qa >= amthr) {
                    float iou = inter / uni;            // exact IEEE == numpy
                    if (iou > bv) { bv = iou; bi = n; } // strict >: first max
                }
            }
        }
    }

    // ---------------- Phase B: column (wave-uniform, rare) ----------------
    {
        unsigned cms[4] = {cm0, cm1, cm2, cm3};
        #pragma unroll
        for (int h = 0; h < 4; h++) {
            unsigned wc = cms[h];
            #pragma unroll
            for (int off = 32; off > 0; off >>= 1)
                wc |= __shfl_xor(wc, off);               // wave-OR (uniform)
            const int nb = h * 32;
            while (wc) {
                int n = __builtin_ctz(wc) + nb;
                wc &= wc - 1;
                float inter, uni;
                geom(axy, sg[n], area_a, sarea[n], inter, uni);
                float qa = inter * __builtin_amdgcn_rcpf(uni);
                bool cc = valid && (qa >= scurf[n]);     // warmed re-test
                if (__any((int)cc)) {
                    float iou = inter / uni;             // exact IEEE == numpy
                    // winner always passes cc (scurf <= colM*(1-3.2e-7)),
                    // so reducing over cc lanes only is safe
                    unsigned qb = cc ? __float_as_uint(iou) : 0u;
                    unsigned mm = qb;
                    #pragma unroll
                    for (int off = 32; off > 0; off >>= 1) {
                        unsigned o = __shfl_xor(mm, off);
                        mm = o > mm ? o : mm;
                    }
                    unsigned long long ball =
                        __ballot((int)(qb == mm && mm > 0u));
                    if (ball) {
                        int leader = __ffsll((long long)ball) - 1; // lowest a
                        if ((tid & 63) == leader) {
                            unsigned long long v =
                                (((unsigned long long)mm) << 32) |
                                (unsigned long long)(unsigned)(AA - a);
                            atomicMax(colmax + b * NN + n, v);
                            atomicMax((unsigned*)&scurf[n],
                                __float_as_uint(__uint_as_float(mm) * DEFL));
                        }
                    }
                }
            }
        }
    }

    if (valid) {
        const size_t base = (size_t)b * AA + a;
        out_val[base] = bv;
        out_slot[base] = bi;
    }
}

// ---------------------------------------------------------------------------
// Scatter gt->anchor override: np fancy-assignment last-n-wins ==
// atomicMax over (OVR_FLAG + n). lowkey==0 (memset init) rejected by guard.
// ---------------------------------------------------------------------------
__global__ void scatter_kernel(const unsigned long long* __restrict__ colmax,
                               int* __restrict__ out_slot) {
    const int b = blockIdx.x;
    const int n = threadIdx.x;
    if (n < NN) {
        unsigned long long v = colmax[b * NN + n];
        unsigned low = (unsigned)(v & 0xFFFFFFFFull);
        if (low >= 1u && low <= (unsigned)AA) {
            int idx = AA - (int)low;
            atomicMax(&out_slot[(size_t)b * AA + idx], OVR_FLAG + n);
        }
    }
}

// ---------------------------------------------------------------------------
// Encode: read row val/slot, apply override, encode boxes, write outputs.
// Overwrites the boxes region (incl. colmax scratch bytes).
// ---------------------------------------------------------------------------
__global__ __launch_bounds__(256) void encode_kernel(
        const int* __restrict__ gt_labels,
        const float4* __restrict__ gt_boxes,        // xyxy
        const float4* __restrict__ anchors_cxcywh,
        float* __restrict__ out)
{
    const int b = blockIdx.y;
    const int tid = threadIdx.x;
    const int a = blockIdx.x * 256 + tid;

    __shared__ float4 sg[NN];
    __shared__ int    slab[NN];
    if (tid < NN) {
        sg[tid]   = gt_boxes[b * NN + tid];
        slab[tid] = gt_labels[b * NN + tid];
    }
    __syncthreads();
    if (a >= AA) return;

    const size_t BA = (size_t)BB * AA;
    const size_t base = (size_t)b * AA + a;

    float bv = out[base];
    int s = ((const int*)(out + 5 * BA))[base];

    int idx; float val;
    if (s >= OVR_FLAG) { idx = s - OVR_FLAG; val = 2.0f; }
    else               { idx = s;            val = bv;   }
    const bool pos = val > 0.5f;

    const float4 g = sg[idx];
    const float gcx = (g.x + g.z) * 0.5f;
    const float gcy = (g.y + g.w) * 0.5f;
    const float gw  = g.z - g.x;
    const float gh  = g.w - g.y;

    const float4 anc = anchors_cxcywh[a];
    const float ecx = (gcx - anc.x) / anc.z;
    const float ecy = (gcy - anc.y) / anc.w;
    const float ew  = logf((gw + EPS_F) / (anc.z + EPS_F));
    const float eh  = logf((gh + EPS_F) / (anc.w + EPS_F));

    out[base] = pos ? (float)slab[idx] : 0.0f;                   // labels
    ((float4*)(out + BA))[base] = make_float4(ecx, ecy, ew, eh); // boxes
    out[5 * BA + base] = pos ? 1.0f : 0.0f;                      // mask
}

extern "C" void kernel_launch(void* const* d_in, const int* in_sizes, int n_in,
                              void* d_out, int out_size, void* d_ws, size_t ws_size,
                              hipStream_t stream) {
    const int*    gt_labels    = (const int*)d_in[0];
    const float4* gt_boxes     = (const float4*)d_in[1];
    const float4* anchors_cxcy = (const float4*)d_in[2];
    const float4* anchors_xyxy = (const float4*)d_in[3];
    float* out = (float*)d_out;

    const size_t BA = (size_t)BB * AA;
    unsigned long long* colmax = (unsigned long long*)(out + BA); // 8B-aligned
    int* slot = (int*)(out + 5 * BA);

    (void)hipMemsetAsync(colmax, 0,
                         (size_t)BB * NN * sizeof(unsigned long long), stream);

    dim3 grid((AA + 255) / 256, BB);
    iou_pass_kernel<<<grid, 256, 0, stream>>>(gt_boxes, anchors_xyxy, colmax,
                                              out, slot);
    scatter_kernel<<<BB, 128, 0, stream>>>(colmax, slot);
    encode_kernel<<<grid, 256, 0, stream>>>(gt_labels, gt_boxes, anchors_cxcy,
                                            out);
}

// Round 11
// 142.568 us; speedup vs baseline: 1.0695x; 1.0205x over previous
//
#include <hip/hip_runtime.h>
#include <math.h>

// CRITICAL: ban FMA contraction file-wide. 1-ulp iou shifts flip near-tie
// argmaxes vs numpy's correctly-rounded ref (rounds 2-4, absmax 69).
#pragma clang fp contract(off)

// Shapes: B=64, N=100, A=8732.
// Out layout (f32 flat): [0,BA) labels | [BA,5BA) boxes | [5BA,6BA) mask
// iou_pass writes: row max iou -> labels region, row argmax -> mask region.
// colmax u64[B*N] at out+BA (boxes region): initialized by prior_kernel,
// atomicMax'd by iou_pass, consumed by scatter, overwritten by encode.
// d_ws: prior f32[B*N] = 25,600 B (proven-safe size).

#define AA 8732
#define NN 100
#define BB 64
#define EPS_F 1e-6f
#define OVR_FLAG 0x10000
// qa = inter*v_rcp(uni): rel err <= ~1.8e-7. DEFL=1-5e-7 deflation makes all
// filters rigorous one-sided bounds (HW-validated rounds 8/10).
#define DEFL 0.9999995f

__constant__ int FM_SIZE[6] = {38, 19, 10, 5, 3, 1};
__constant__ int FM_NF[6]   = {4, 6, 6, 6, 4, 4};
__constant__ int FM_OFF[6]  = {0, 5776, 7942, 8542, 8692, 8728};

__device__ __forceinline__ void geom(const float4 axy, const float4 g,
                                     float area_a, float ag,
                                     float& inter, float& uni) {
    float ltx = fmaxf(axy.x, g.x);
    float lty = fmaxf(axy.y, g.y);
    float rbx = fminf(axy.z, g.z);
    float rby = fminf(axy.w, g.w);
    float w = fmaxf(rbx - ltx, 0.0f);
    float h = fmaxf(rby - lty, 0.0f);
    inter = w * h;
    uni = area_a + ag - inter;       // uni >= max area > 0 always
}

// ---------------------------------------------------------------------------
// Prior (separate tiny kernel — r10's in-block version was computed 35x
// redundantly with scattered loads; this is the r7-proven shape):
// per (b,n), rcp-approx max IoU over the <=30 center-cell anchors, deflated
// => SAFE lower bound of the column max. Also initializes colmax with
// (prior_bits<<32 | 0): <= true packed max (low=0 loses ties), so the real
// winner's atomicMax always lands; removes the memset dispatch.
// ---------------------------------------------------------------------------
__global__ void prior_kernel(const float4* __restrict__ gt_boxes,
                             const float4* __restrict__ anchors_xyxy,
                             float* __restrict__ prior,
                             unsigned long long* __restrict__ colmax) {
    const int b = blockIdx.x;
    const int n = threadIdx.x;
    if (n >= NN) return;
    float4 g = gt_boxes[b * NN + n];
    float ag = (g.z - g.x) * (g.w - g.y);
    float cx = (g.x + g.z) * 0.5f;
    float cy = (g.y + g.w) * 0.5f;
    float best = 0.0f;
    for (int f = 0; f < 6; f++) {
        int s = FM_SIZE[f];
        int j = (int)(cx * (float)s); j = j < s - 1 ? j : s - 1;
        int i = (int)(cy * (float)s); i = i < s - 1 ? i : s - 1;
        int base = FM_OFF[f] + (i * s + j) * FM_NF[f];
        for (int k = 0; k < FM_NF[f]; k++) {
            float4 an = anchors_xyxy[base + k];
            float area_a = (an.z - an.x) * (an.w - an.y);
            float inter, uni;
            geom(an, g, area_a, ag, inter, uni);
            best = fmaxf(best, inter * __builtin_amdgcn_rcpf(uni));
        }
    }
    float defl = best * DEFL;        // <= colM*(1-3.2e-7): safe lower bound
    prior[b * NN + n] = defl;
    colmax[b * NN + n] = ((unsigned long long)__float_as_uint(defl)) << 32;
}

// ---------------------------------------------------------------------------
// Main-pass chunk [N0,N1): 2 anchors per thread sharing the LDS reads.
// Row: per-lane record masks (qa >= running am*DEFL), deferred exact div.
// Col: r7-style per-iter __any trigger (rare after prior priming); on
// trigger, exact divs + packed u64 butterfly max ((bits<<32)|(AA-a): max
// iou then lowest a — resolves ALL ties incl. the 2-anchors-per-lane case),
// lane 0 submits atomicMax + scurf warm-up.
// ---------------------------------------------------------------------------
template <int N0, int N1>
__device__ __forceinline__ void passChunk(
        const float4 x0, const float4 x1,
        const float ar0, const float ar1,
        const bool v0, const bool v1,
        const int a0, const int a1,
        const int b, const int tid,
        const float4* __restrict__ sg,
        const float* __restrict__ sarea,
        float* scurf,
        unsigned long long* __restrict__ colmax,
        float& am0, float& am1,
        unsigned& rm0, unsigned& rm1)
{
    #pragma unroll 4
    for (int n = N0; n < N1; n++) {
        float4 g = sg[n];
        float ag = sarea[n];
        float i0, u0, i1, u1;
        geom(x0, g, ar0, ag, i0, u0);
        geom(x1, g, ar1, ag, i1, u1);
        float q0 = i0 * __builtin_amdgcn_rcpf(u0);
        float q1 = i1 * __builtin_amdgcn_rcpf(u1);
        bool r0 = (q0 > 0.0f) && (q0 >= am0 * DEFL);   // row near-record
        bool r1 = (q1 > 0.0f) && (q1 >= am1 * DEFL);
        am0 = fmaxf(am0, q0);
        am1 = fmaxf(am1, q1);
        rm0 |= (r0 ? 1u : 0u) << (n - N0);
        rm1 |= (r1 ? 1u : 0u) << (n - N0);
        float cf = scurf[n];
        bool c0 = v0 && (q0 >= cf);                    // column candidate
        bool c1 = v1 && (q1 >= cf);
        if (__any((int)(c0 | c1))) {                   // rare
            float iou0 = i0 / u0;                      // exact IEEE == numpy
            float iou1 = i1 / u1;
            unsigned long long p0 = c0
                ? ((((unsigned long long)__float_as_uint(iou0)) << 32) |
                   (unsigned long long)(unsigned)(AA - a0)) : 0ull;
            unsigned long long p1 = c1
                ? ((((unsigned long long)__float_as_uint(iou1)) << 32) |
                   (unsigned long long)(unsigned)(AA - a1)) : 0ull;
            unsigned long long p = p0 > p1 ? p0 : p1;
            #pragma unroll
            for (int off = 32; off > 0; off >>= 1) {
                unsigned long long o = __shfl_xor(p, off);
                p = o > p ? o : p;
            }
            if ((tid & 63) == 0 && p != 0ull) {
                atomicMax(colmax + b * NN + n, p);
                float nb = __uint_as_float((unsigned)(p >> 32)) * DEFL;
                atomicMax((unsigned*)&scurf[n], __float_as_uint(nb));
            }
        }
    }
}

// Row Phase B: walk record bits ascending (numpy order), retest vs final
// am*DEFL, exact div only for survivors (sole decision-maker, strict >).
__device__ __forceinline__ void rowScan(const float4 axy, const float area_a,
        const float4* __restrict__ sg, const float* __restrict__ sarea,
        const float amthr, const unsigned* rm, float& bv, int& bi)
{
    #pragma unroll
    for (int h = 0; h < 4; h++) {
        unsigned m = rm[h];
        const int nb = h * 32;
        while (m) {
            int n = __builtin_ctz(m) + nb;
            m &= m - 1;
            float inter, uni;
            geom(axy, sg[n], area_a, sarea[n], inter, uni);
            float qa = inter * __builtin_amdgcn_rcpf(uni);
            if (qa > 0.0f && qa >= amthr) {
                float iou = inter / uni;                // exact IEEE == numpy
                if (iou > bv) { bv = iou; bi = n; }     // strict >: first max
            }
        }
    }
}

__global__ __launch_bounds__(256) void iou_pass_kernel(
        const float4* __restrict__ gt_boxes,        // B*N xyxy
        const float4* __restrict__ anchors_xyxy,    // A
        const float* __restrict__ prior,            // B*N (deflated)
        unsigned long long* __restrict__ colmax,    // B*N packed, init by prior
        float* __restrict__ out_val,                // -> out[0..BA)
        int* __restrict__ out_slot)                 // -> out[5BA..6BA)
{
    const int b = blockIdx.y;
    const int tid = threadIdx.x;
    const int a0 = blockIdx.x * 512 + tid;          // 2 anchors per thread
    const int a1 = a0 + 256;
    const bool v0 = (a0 < AA), v1 = (a1 < AA);
    const int ac0 = v0 ? a0 : (AA - 1);
    const int ac1 = v1 ? a1 : (AA - 1);

    __shared__ float4 sg[NN];
    __shared__ float  sarea[NN];
    __shared__ float  scurf[NN];

    if (tid < NN) {
        float4 g = gt_boxes[b * NN + tid];
        sg[tid] = g;
        sarea[tid] = (g.z - g.x) * (g.w - g.y);
        scurf[tid] = prior[b * NN + tid];
    }
    __syncthreads();

    const float4 x0 = anchors_xyxy[ac0];
    const float4 x1 = anchors_xyxy[ac1];
    const float ar0 = (x0.z - x0.x) * (x0.w - x0.y);
    const float ar1 = (x1.z - x1.x) * (x1.w - x1.y);

    float am0 = 0.0f, am1 = 0.0f;
    unsigned r0c0 = 0, r0c1 = 0, r0c2 = 0, r0c3 = 0;
    unsigned r1c0 = 0, r1c1 = 0, r1c2 = 0, r1c3 = 0;
    passChunk<0, 32>(x0, x1, ar0, ar1, v0, v1, a0, a1, b, tid,
                     sg, sarea, scurf, colmax, am0, am1, r0c0, r1c0);
    passChunk<32, 64>(x0, x1, ar0, ar1, v0, v1, a0, a1, b, tid,
                      sg, sarea, scurf, colmax, am0, am1, r0c1, r1c1);
    passChunk<64, 96>(x0, x1, ar0, ar1, v0, v1, a0, a1, b, tid,
                      sg, sarea, scurf, colmax, am0, am1, r0c2, r1c2);
    passChunk<96, NN>(x0, x1, ar0, ar1, v0, v1, a0, a1, b, tid,
                      sg, sarea, scurf, colmax, am0, am1, r0c3, r1c3);

    {
        unsigned rmA[4] = {r0c0, r0c1, r0c2, r0c3};
        float bv = 0.0f; int bi = 0;     // zero row: bv=0, bi=0 == numpy
        rowScan(x0, ar0, sg, sarea, am0 * DEFL, rmA, bv, bi);
        if (v0) {
            const size_t base = (size_t)b * AA + a0;
            out_val[base] = bv;
            out_slot[base] = bi;
        }
    }
    {
        unsigned rmB[4] = {r1c0, r1c1, r1c2, r1c3};
        float bv = 0.0f; int bi = 0;
        rowScan(x1, ar1, sg, sarea, am1 * DEFL, rmB, bv, bi);
        if (v1) {
            const size_t base = (size_t)b * AA + a1;
            out_val[base] = bv;
            out_slot[base] = bi;
        }
    }
}

// ---------------------------------------------------------------------------
// Scatter gt->anchor override: np fancy-assignment last-n-wins ==
// atomicMax over (OVR_FLAG + n). low==0 (prior sentinel) rejected by guard.
// ---------------------------------------------------------------------------
__global__ void scatter_kernel(const unsigned long long* __restrict__ colmax,
                               int* __restrict__ out_slot) {
    const int b = blockIdx.x;
    const int n = threadIdx.x;
    if (n < NN) {
        unsigned long long v = colmax[b * NN + n];
        unsigned low = (unsigned)(v & 0xFFFFFFFFull);
        if (low >= 1u && low <= (unsigned)AA) {
            int idx = AA - (int)low;
            atomicMax(&out_slot[(size_t)b * AA + idx], OVR_FLAG + n);
        }
    }
}

// ---------------------------------------------------------------------------
// Encode: read row val/slot, apply override, encode boxes, write outputs.
// Overwrites the boxes region (incl. colmax scratch bytes).
// ---------------------------------------------------------------------------
__global__ __launch_bounds__(256) void encode_kernel(
        const int* __restrict__ gt_labels,
        const float4* __restrict__ gt_boxes,        // xyxy
        const float4* __restrict__ anchors_cxcywh,
        float* __restrict__ out)
{
    const int b = blockIdx.y;
    const int tid = threadIdx.x;
    const int a = blockIdx.x * 256 + tid;

    __shared__ float4 sg[NN];
    __shared__ int    slab[NN];
    if (tid < NN) {
        sg[tid]   = gt_boxes[b * NN + tid];
        slab[tid] = gt_labels[b * NN + tid];
    }
    __syncthreads();
    if (a >= AA) return;

    const size_t BA = (size_t)BB * AA;
    const size_t base = (size_t)b * AA + a;

    float bv = out[base];
    int s = ((const int*)(out + 5 * BA))[base];

    int idx; float val;
    if (s >= OVR_FLAG) { idx = s - OVR_FLAG; val = 2.0f; }
    else               { idx = s;            val = bv;   }
    const bool pos = val > 0.5f;

    const float4 g = sg[idx];
    const float gcx = (g.x + g.z) * 0.5f;
    const float gcy = (g.y + g.w) * 0.5f;
    const float gw  = g.z - g.x;
    const float gh  = g.w - g.y;

    const float4 anc = anchors_cxcywh[a];
    const float ecx = (gcx - anc.x) / anc.z;
    const float ecy = (gcy - anc.y) / anc.w;
    const float ew  = logf((gw + EPS_F) / (anc.z + EPS_F));
    const float eh  = logf((gh + EPS_F) / (anc.w + EPS_F));

    out[base] = pos ? (float)slab[idx] : 0.0f;                   // labels
    ((float4*)(out + BA))[base] = make_float4(ecx, ecy, ew, eh); // boxes
    out[5 * BA + base] = pos ? 1.0f : 0.0f;                      // mask
}

extern "C" void kernel_launch(void* const* d_in, const int* in_sizes, int n_in,
                              void* d_out, int out_size, void* d_ws, size_t ws_size,
                              hipStream_t stream) {
    const int*    gt_labels    = (const int*)d_in[0];
    const float4* gt_boxes     = (const float4*)d_in[1];
    const float4* anchors_cxcy = (const float4*)d_in[2];
    const float4* anchors_xyxy = (const float4*)d_in[3];
    float* out = (float*)d_out;

    const size_t BA = (size_t)BB * AA;
    unsigned long long* colmax = (unsigned long long*)(out + BA); // 8B-aligned
    int* slot = (int*)(out + 5 * BA);
    float* prior = (float*)d_ws;        // B*N f32 = 25,600 B (proven size)

    prior_kernel<<<BB, 128, 0, stream>>>(gt_boxes, anchors_xyxy, prior, colmax);

    dim3 grid((AA + 511) / 512, BB);    // (18, 64), 2 anchors/thread
    iou_pass_kernel<<<grid, 256, 0, stream>>>(gt_boxes, anchors_xyxy, prior,
                                              colmax, out, slot);
    scatter_kernel<<<BB, 128, 0, stream>>>(colmax, slot);

    dim3 grid2((AA + 255) / 256, BB);   // (35, 64)
    encode_kernel<<<grid2, 256, 0, stream>>>(gt_labels, gt_boxes, anchors_cxcy,
                                             out);
}

// Round 12
// 130.570 us; speedup vs baseline: 1.1678x; 1.0919x over previous
//
#include <hip/hip_runtime.h>
#include <math.h>

// CRITICAL: ban FMA contraction file-wide. 1-ulp iou shifts flip near-tie
// argmaxes vs numpy's correctly-rounded ref (rounds 2-4, absmax 69).
#pragma clang fp contract(off)

// Shapes: B=64, N=100, A=8732.
// Out layout (f32 flat): [0,BA) labels | [BA,5BA) boxes | [5BA,6BA) mask
// iou_pass writes ONLY the slot array (mask region): bi | 0x8000 pos bit.
// colmax u64[B*N] at out+BA (boxes region): initialized by prior_kernel,
// atomicMax'd by iou_pass, consumed by scatter, overwritten by encode.
// d_ws: prior f32[B*N] = 25,600 B (proven-safe size).

#define AA 8732
#define NN 100
#define BB 64
#define EPS_F 1e-6f
#define OVR_FLAG 0x10000
#define POS_BIT  0x8000
// qa = inter*v_rcp(uni): rel err <= ~1.8e-7. DEFL=1-5e-7 deflation makes all
// filters rigorous one-sided bounds (HW-validated rounds 8/10/11).
#define DEFL 0.9999995f

__constant__ int FM_SIZE[6] = {38, 19, 10, 5, 3, 1};
__constant__ int FM_NF[6]   = {4, 6, 6, 6, 4, 4};
__constant__ int FM_OFF[6]  = {0, 5776, 7942, 8542, 8692, 8728};

__device__ __forceinline__ void geom(const float4 axy, const float4 g,
                                     float area_a, float ag,
                                     float& inter, float& uni) {
    float ltx = fmaxf(axy.x, g.x);
    float lty = fmaxf(axy.y, g.y);
    float rbx = fminf(axy.z, g.z);
    float rby = fminf(axy.w, g.w);
    float w = fmaxf(rbx - ltx, 0.0f);
    float h = fmaxf(rby - lty, 0.0f);
    inter = w * h;
    uni = area_a + ag - inter;       // uni >= max area > 0 always
}

// ---------------------------------------------------------------------------
// Prior: per (b,n), rcp-approx max IoU over the <=30 center-cell anchors,
// deflated => SAFE lower bound of the column max (< true bits strictly).
// Also initializes colmax with (prior_bits<<32 | 0): low=0 loses all ties to
// genuine submissions (low>=1), so the real winner always lands; removes the
// memset dispatch.
// ---------------------------------------------------------------------------
__global__ void prior_kernel(const float4* __restrict__ gt_boxes,
                             const float4* __restrict__ anchors_xyxy,
                             float* __restrict__ prior,
                             unsigned long long* __restrict__ colmax) {
    const int b = blockIdx.x;
    const int n = threadIdx.x;
    if (n >= NN) return;
    float4 g = gt_boxes[b * NN + n];
    float ag = (g.z - g.x) * (g.w - g.y);
    float cx = (g.x + g.z) * 0.5f;
    float cy = (g.y + g.w) * 0.5f;
    float best = 0.0f;
    for (int f = 0; f < 6; f++) {
        int s = FM_SIZE[f];
        int j = (int)(cx * (float)s); j = j < s - 1 ? j : s - 1;
        int i = (int)(cy * (float)s); i = i < s - 1 ? i : s - 1;
        int base = FM_OFF[f] + (i * s + j) * FM_NF[f];
        for (int k = 0; k < FM_NF[f]; k++) {
            float4 an = anchors_xyxy[base + k];
            float area_a = (an.z - an.x) * (an.w - an.y);
            float inter, uni;
            geom(an, g, area_a, ag, inter, uni);
            best = fmaxf(best, inter * __builtin_amdgcn_rcpf(uni));
        }
    }
    float defl = best * DEFL;        // <= colM*(1-3.2e-7): safe lower bound
    prior[b * NN + n] = defl;
    colmax[b * NN + n] = ((unsigned long long)__float_as_uint(defl)) << 32;
}

// ---------------------------------------------------------------------------
// Main-pass chunk [N0,N1): 1 anchor/thread (2240 blocks: occupancy regime
// proven in r5/r7 — r11's 2/thread halved the grid and sank occupancy to 28%).
// Row: record mask vs pre-deflated running threshold rt (loop-carried chain
// is a single fmax; qa*DEFL is off the critical path); exact div deferred.
// Col: 1-cmp __any trigger vs LDS scurf (rare after prior priming); on
// trigger, exact div + packed u64 butterfly ((bits<<32)|(AA-a): max iou then
// lowest a), lane 0 submits atomicMax + scurf warm-up. `valid` dropped from
// the column path: clamped clone lanes carry anchor AA-1's genuine packed
// value — idempotent under max.
// ---------------------------------------------------------------------------
template <int N0, int N1>
__device__ __forceinline__ void passChunk(
        const float4 axy, const float area_a, const unsigned lowkey,
        const int b, const int tid,
        const float4* __restrict__ sg,
        float2* sac,                                // x=area, y=scurf
        unsigned long long* __restrict__ colmax,
        float& rt, unsigned& rm)
{
    #pragma unroll 4
    for (int n = N0; n < N1; n++) {
        float4 g = sg[n];
        float2 aw = sac[n];        // one ds_read_b64 (stale .y = superset, safe)
        float inter, uni;
        geom(axy, g, area_a, aw.x, inter, uni);
        float qa = inter * __builtin_amdgcn_rcpf(uni);
        bool r = (qa > 0.0f) && (qa >= rt);          // row near-record
        rt = fmaxf(rt, qa * DEFL);
        rm |= (r ? 1u : 0u) << (n - N0);
        if (__any((int)(qa >= aw.y))) {              // column trigger (rare)
            float iou = inter / uni;                 // exact IEEE == numpy
            bool cc = (qa >= aw.y);
            unsigned long long p = cc
                ? ((((unsigned long long)__float_as_uint(iou)) << 32) |
                   (unsigned long long)lowkey) : 0ull;
            #pragma unroll
            for (int off = 32; off > 0; off >>= 1) {
                unsigned long long o = __shfl_xor(p, off);
                p = o > p ? o : p;
            }
            if ((tid & 63) == 0 && p != 0ull) {
                atomicMax(colmax + b * NN + n, p);
                atomicMax((unsigned*)&sac[n].y,
                    __float_as_uint(__uint_as_float((unsigned)(p >> 32)) * DEFL));
            }
        }
    }
}

__global__ __launch_bounds__(256) void iou_pass_kernel(
        const float4* __restrict__ gt_boxes,        // B*N xyxy
        const float4* __restrict__ anchors_xyxy,    // A
        const float* __restrict__ prior,            // B*N (deflated)
        unsigned long long* __restrict__ colmax,    // B*N packed, prior-init
        int* __restrict__ out_slot)                 // -> out[5BA..6BA)
{
    const int b = blockIdx.y;
    const int tid = threadIdx.x;
    const int a = blockIdx.x * 256 + tid;
    const bool valid = (a < AA);
    const int ac = valid ? a : (AA - 1);

    __shared__ float4 sg[NN];
    __shared__ float2 sac[NN];     // x=area_g, y=scurf (deflated lower bound)

    if (tid < NN) {
        float4 g = gt_boxes[b * NN + tid];
        sg[tid] = g;
        sac[tid] = make_float2((g.z - g.x) * (g.w - g.y),
                               prior[b * NN + tid]);
    }
    __syncthreads();

    const float4 axy = anchors_xyxy[ac];
    const float area_a = (axy.z - axy.x) * (axy.w - axy.y);
    const unsigned lowkey = (unsigned)(AA - ac);    // bigger = lower anchor

    // ---------------- Phase A ----------------
    float rt = 0.0f;               // running (deflated) row-record threshold
    unsigned rm0 = 0, rm1 = 0, rm2 = 0, rm3 = 0;
    passChunk<0, 32>(axy, area_a, lowkey, b, tid, sg, sac, colmax, rt, rm0);
    passChunk<32, 64>(axy, area_a, lowkey, b, tid, sg, sac, colmax, rt, rm1);
    passChunk<64, 96>(axy, area_a, lowkey, b, tid, sg, sac, colmax, rt, rm2);
    passChunk<96, NN>(axy, area_a, lowkey, b, tid, sg, sac, colmax, rt, rm3);

    // ---------------- Phase B: row replay (ascending n = numpy order) -----
    float bv = 0.0f;   // all-zero row: bv=0, bi=0 == numpy argmax
    int bi = 0;
    unsigned rms[4] = {rm0, rm1, rm2, rm3};
    #pragma unroll
    for (int h = 0; h < 4; h++) {
        unsigned m = rms[h];
        const int nb = h * 32;
        while (m) {
            int n = __builtin_ctz(m) + nb;
            m &= m - 1;
            float inter, uni;
            geom(axy, sg[n], area_a, sac[n].x, inter, uni);
            float qa = inter * __builtin_amdgcn_rcpf(uni);
            if (qa > 0.0f && qa >= rt) {             // final-threshold re-test
                float iou = inter / uni;             // exact IEEE == numpy
                if (iou > bv) { bv = iou; bi = n; }  // strict >: first max
            }
        }
    }

    if (valid) {
        // pos decision folded into the slot: exact bv vs 0.5 (override makes
        // pos true anyway and is applied later via OVR_FLAG > POS_BIT|bi).
        out_slot[(size_t)b * AA + a] = bi | (bv > 0.5f ? POS_BIT : 0);
    }
}

// ---------------------------------------------------------------------------
// Scatter gt->anchor override: np fancy-assignment last-n-wins ==
// atomicMax over (OVR_FLAG + n). low==0 (prior sentinel) rejected by guard.
// OVR_FLAG (0x10000) dominates any POS_BIT|bi (<=0x8063).
// ---------------------------------------------------------------------------
__global__ void scatter_kernel(const unsigned long long* __restrict__ colmax,
                               int* __restrict__ out_slot) {
    const int b = blockIdx.x;
    const int n = threadIdx.x;
    if (n < NN) {
        unsigned long long v = colmax[b * NN + n];
        unsigned low = (unsigned)(v & 0xFFFFFFFFull);
        if (low >= 1u && low <= (unsigned)AA) {
            int idx = AA - (int)low;
            atomicMax(&out_slot[(size_t)b * AA + idx], OVR_FLAG + n);
        }
    }
}

// ---------------------------------------------------------------------------
// Encode: decode slot (override / pos / idx), encode boxes, write all three
// outputs. Overwrites the boxes region (incl. colmax scratch bytes).
// ---------------------------------------------------------------------------
__global__ __launch_bounds__(256) void encode_kernel(
        const int* __restrict__ gt_labels,
        const float4* __restrict__ gt_boxes,        // xyxy
        const float4* __restrict__ anchors_cxcywh,
        float* __restrict__ out)
{
    const int b = blockIdx.y;
    const int tid = threadIdx.x;
    const int a = blockIdx.x * 256 + tid;

    __shared__ float4 sg[NN];
    __shared__ int    slab[NN];
    if (tid < NN) {
        sg[tid]   = gt_boxes[b * NN + tid];
        slab[tid] = gt_labels[b * NN + tid];
    }
    __syncthreads();
    if (a >= AA) return;

    const size_t BA = (size_t)BB * AA;
    const size_t base = (size_t)b * AA + a;

    int s = ((const int*)(out + 5 * BA))[base];

    int idx; bool pos;
    if (s >= OVR_FLAG) { idx = s - OVR_FLAG;  pos = true; }
    else               { idx = s & 0x7FFF;    pos = (s & POS_BIT) != 0; }

    const float4 g = sg[idx];
    const float gcx = (g.x + g.z) * 0.5f;
    const float gcy = (g.y + g.w) * 0.5f;
    const float gw  = g.z - g.x;
    const float gh  = g.w - g.y;

    const float4 anc = anchors_cxcywh[a];
    const float ecx = (gcx - anc.x) / anc.z;
    const float ecy = (gcy - anc.y) / anc.w;
    const float ew  = logf((gw + EPS_F) / (anc.z + EPS_F));
    const float eh  = logf((gh + EPS_F) / (anc.w + EPS_F));

    out[base] = pos ? (float)slab[idx] : 0.0f;                   // labels
    ((float4*)(out + BA))[base] = make_float4(ecx, ecy, ew, eh); // boxes
    out[5 * BA + base] = pos ? 1.0f : 0.0f;                      // mask
}

extern "C" void kernel_launch(void* const* d_in, const int* in_sizes, int n_in,
                              void* d_out, int out_size, void* d_ws, size_t ws_size,
                              hipStream_t stream) {
    const int*    gt_labels    = (const int*)d_in[0];
    const float4* gt_boxes     = (const float4*)d_in[1];
    const float4* anchors_cxcy = (const float4*)d_in[2];
    const float4* anchors_xyxy = (const float4*)d_in[3];
    float* out = (float*)d_out;

    const size_t BA = (size_t)BB * AA;
    unsigned long long* colmax = (unsigned long long*)(out + BA); // 8B-aligned
    int* slot = (int*)(out + 5 * BA);
    float* prior = (float*)d_ws;        // B*N f32 = 25,600 B (proven size)

    prior_kernel<<<BB, 128, 0, stream>>>(gt_boxes, anchors_xyxy, prior, colmax);

    dim3 grid((AA + 255) / 256, BB);    // (35, 64) — 1 anchor/thread
    iou_pass_kernel<<<grid, 256, 0, stream>>>(gt_boxes, anchors_xyxy, prior,
                                              colmax, slot);
    scatter_kernel<<<BB, 128, 0, stream>>>(colmax, slot);
    encode_kernel<<<grid, 256, 0, stream>>>(gt_labels, gt_boxes, anchors_cxcy,
                                            out);
}